// Round 13
// baseline (11484.850 us; speedup 1.0000x reference)
//
#include <hip/hip_runtime.h>

typedef unsigned int uint;
typedef unsigned short ushort;
typedef unsigned long long u64;
typedef __attribute__((ext_vector_type(8))) short bf16x8;
typedef __attribute__((ext_vector_type(4))) float f32x4;

// Problem constants
#define T_STEPS 512
#define BATCH   512
#define NB      4        // batch rows per block (2 blocks/CU co-resident)
#define NREP    128
#define XS      104      // xi plane row stride (ushort)
#define HS      40       // h ring row stride (ushort)
#define HZROW   48       // zero row index in h planes (12 slots * 4 rows)
#define CSLOT   512      // c-ring floats per slot (128 sidx * 4 rows)
#define OUTC    96
#define FSTR    32       // flag stride in uints (128B line per flag)
#define NITER   256      // 2 steps per iteration
#define PAY     192      // u64 per (slot,rep) hop payload (4 rows x 96 x 2 planes)

__device__ __forceinline__ ushort f2bf(float f){
  uint u = __builtin_bit_cast(uint, f);
  u = (u + 0x7FFFu + ((u >> 16) & 1u)) >> 16;   // RNE
  return (ushort)u;
}
__device__ __forceinline__ float bf2f(ushort h){
  uint u = ((uint)h) << 16; return __builtin_bit_cast(float, u);
}
__device__ __forceinline__ float sigm(float x){
  float e = __builtin_exp2f(-1.44269504f * x);
  return __builtin_amdgcn_rcpf(1.0f + e);
}
__device__ __forceinline__ float tanh_fast(float x){
  float e = __builtin_exp2f(-2.88539008f * x);
  return 2.0f * __builtin_amdgcn_rcpf(1.0f + e) - 1.0f;
}
__device__ __forceinline__ uint aload32(const uint* p){
  return __hip_atomic_load(p, __ATOMIC_RELAXED, __HIP_MEMORY_SCOPE_AGENT);
}
__device__ __forceinline__ void astore32(uint* p, uint v){
  __hip_atomic_store(p, v, __ATOMIC_RELAXED, __HIP_MEMORY_SCOPE_AGENT);
}
__device__ __forceinline__ u64 aload64(const u64* p){
  return __hip_atomic_load(p, __ATOMIC_RELAXED, __HIP_MEMORY_SCOPE_AGENT);
}
__device__ __forceinline__ void astore64(u64* p, u64 v){
  __hip_atomic_store(p, v, __ATOMIC_RELAXED, __HIP_MEMORY_SCOPE_AGENT);
}

// 4-stage pipeline, 128 reps of 4 batch rows: 512 blocks x 256 threads ->
// TWO co-resident blocks per CU so one block's barrier/LLC stalls overlap the
// other's execution (rounds 3-12 were 1 block/CU lockstep: ~58% all-pipe
// idle, invariant to every protocol change). Each wave owns 32 gate-columns
// (2 groups of 16). LDS ~58KB; launch_bounds(256,2) caps 256 VGPR/wave so
// 2-block packing is guaranteed. With rd>=512 producers free-run (no
// downstream checks) so scheduling degradations stay deadlock-free.
__global__ __launch_bounds__(256, 2)
void rnn_pipeline(const float* __restrict__ x,
                  const float* __restrict__ W0, const float* __restrict__ b0,
                  const float* __restrict__ W1, const float* __restrict__ b1,
                  const float* __restrict__ W2, const float* __restrict__ b2,
                  const float* __restrict__ W3, const float* __restrict__ b3,
                  const float* __restrict__ Wa, const float* __restrict__ ba,
                  float* __restrict__ y_out,
                  uint* __restrict__ prod, uint* __restrict__ consA,
                  uint* __restrict__ consB,
                  u64* __restrict__ hop0, u64* __restrict__ hop1,
                  u64* __restrict__ hop2, int rd)
{
  const int tid  = threadIdx.x;
  const int wv   = tid >> 6;      // wave 0..3
  const int lane = tid & 63;
  const int l15  = lane & 15;
  const int hi   = lane >> 4;     // 0..3
  const int rep  = blockIdx.x & 127;
  const int stage= blockIdx.x >> 7;
  const int b0r  = rep * NB;
  const int rmask= rd - 1;

  const int dil = (stage==0)?1:(stage==1)?3:(stage==2)?6:12;
  const int KIN = (stage==0)?64:96;
  const int K   = KIN + 64;
  const float* Wl = (stage==0)?W0:(stage==1)?W1:(stage==2)?W2:W3;
  const float* bl = (stage==0)?b0:(stage==1)?b1:(stage==2)?b2:b3;

  __shared__ __align__(16) ushort xiA_hi[16*XS], xiA_lo[16*XS];  // step t input
  __shared__ __align__(16) ushort xiB_hi[16*XS], xiB_lo[16*XS];  // step u input
  __shared__ __align__(16) float  sh_c[12*CSLOT];                // c ring
  __shared__ __align__(16) ushort h_hi[(HZROW+1)*HS], h_lo[(HZROW+1)*HS];
  __shared__ __align__(16) ushort outpA[1920], outpB[1920];      // hi@0, lo@384
  __shared__ __align__(16) ushort o1pA[768], o1pB[768];          // stage3 out1
  __shared__ __align__(16) float  o3fA[384],  o3fB[384];         // stage3 out3

  for (int i = tid; i < 16*XS; i += 256){ xiA_hi[i]=0; xiA_lo[i]=0; xiB_hi[i]=0; xiB_lo[i]=0; }
  for (int i = tid; i < 12*CSLOT; i += 256) sh_c[i] = 0.0f;
  for (int i = tid; i < (HZROW+1)*HS; i += 256){ h_hi[i]=0; h_lo[i]=0; }
  for (int i = tid; i < 1920; i += 256){ outpA[i]=0; outpB[i]=0; }
  for (int i = tid; i < 768; i += 256){ o1pA[i]=0; o1pB[i]=0; }
  for (int i = tid; i < 384; i += 256){ o3fA[i]=0.0f; o3fB[i]=0.0f; }

  const int sidx = 32*wv + l15;  // group g owns gate-column sidx + 16*g

  // Layer weights as split-bf16 MFMA B-fragments, 2 state-groups per wave.
  bf16x8 whi[2][4][5], wlo[2][4][5];
  #pragma unroll
  for (int g = 0; g < 2; ++g){
    #pragma unroll
    for (int j = 0; j < 4; ++j){
      const int grow = 128*j + sidx + 16*g;
      #pragma unroll
      for (int ks = 0; ks < 5; ++ks){
        bf16x8 vh, vl;
        const int cb = ks*32 + hi*8;
        if (cb < K){
          const float* p = Wl + (size_t)grow*K + cb;
          #pragma unroll
          for (int q = 0; q < 8; ++q){
            float w = p[q];
            ushort h = f2bf(w);
            vh[q] = (short)h;
            vl[q] = (short)f2bf(w - bf2f(h));
          }
        } else {
          #pragma unroll
          for (int q = 0; q < 8; ++q){ vh[q] = 0; vl[q] = 0; }
        }
        whi[g][j][ks] = vh; wlo[g][j][ks] = vl;
      }
    }
  }
  float bias[2][4];
  #pragma unroll
  for (int g = 0; g < 2; ++g)
    #pragma unroll
    for (int j = 0; j < 4; ++j) bias[g][j] = bl[128*j + sidx + 16*g];

  // Projection weights (stage3): ocol = 16*wv + l15 covers 0..63 (4 waves)
  bf16x8 phi[3], plo[3];
  #pragma unroll
  for (int ks = 0; ks < 3; ++ks){
    bf16x8 z;
    #pragma unroll
    for (int q = 0; q < 8; ++q) z[q]=0;
    phi[ks]=z; plo[ks]=z;
  }
  float bav = 0.0f;
  const int ocol = 16*wv + l15;
  if (stage == 3){
    #pragma unroll
    for (int ks = 0; ks < 3; ++ks){
      const float* p = Wa + (size_t)ocol*96 + ks*32 + hi*8;
      bf16x8 vh, vl;
      #pragma unroll
      for (int q = 0; q < 8; ++q){
        float w = p[q];
        ushort h = f2bf(w);
        vh[q] = (short)h;
        vl[q] = (short)f2bf(w - bf2f(h));
      }
      phi[ks] = vh; plo[ks] = vl;
    }
    bav = ba[ocol];
  }

  // Flag wiring (128 reps, each flag on its own 128B line)
  uint* up_prod  = (stage==1)? &prod[rep*FSTR] : (stage==2)? &prod[(128+rep)*FSTR] :
                   (stage==3)? &prod[(256+rep)*FSTR] : nullptr;
  uint* up_prod1 = (stage==3)? &prod[(128+rep)*FSTR] : nullptr;
  uint* my_prod  = (stage==0)? &prod[rep*FSTR] : (stage==1)? &prod[(128+rep)*FSTR] :
                   (stage==2)? &prod[(256+rep)*FSTR] : nullptr;
  uint* my_consA = (stage==1)? &consA[rep*FSTR] : (stage==2)? &consA[(128+rep)*FSTR] :
                   (stage==3)? &consA[(256+rep)*FSTR] : nullptr;
  uint* my_consB = (stage==3)? &consB[rep*FSTR] : nullptr;
  uint* dnA      = (stage==0)? &consA[rep*FSTR] : (stage==1)? &consA[(128+rep)*FSTR] :
                   (stage==2)? &consA[(256+rep)*FSTR] : nullptr;
  uint* dnB      = (stage==1)? &consB[rep*FSTR] : nullptr;
  const u64* hop_in  = (stage==1)? hop0 : (stage==2)? hop1 : nullptr;
  u64*       hop_out = (stage==0)? hop0 : (stage==1)? hop1 : (stage==2)? hop2 : nullptr;

  // per-lane h-ring read addressing (rows l15>=4 redirect to the zero row)
  const bool hsel   = (l15 < 4);
  const int h_off0  = (hsel ? l15*HS : HZROW*HS) + hi*8;
  const int h_mul   = hsel ? 4*HS : 0;

  auto gemm = [&](const ushort* xhi, const ushort* xlo, int pslot, int dslot,
                  f32x4* a0, f32x4* a1){
    #pragma unroll
    for (int ks = 0; ks < 5; ++ks){
      if (ks*32 < K){
        const ushort *ph, *pl; int off;
        if (ks*32 < KIN){ ph = xhi; pl = xlo; off = l15*XS + hi*8 + ks*32; }
        else if (ks*32 == KIN){ ph = h_hi; pl = h_lo; off = pslot*h_mul + h_off0; }
        else { ph = h_hi; pl = h_lo; off = dslot*h_mul + h_off0; }
        bf16x8 a_hi = *(const bf16x8*)(ph + off);
        bf16x8 a_lo = *(const bf16x8*)(pl + off);
        #pragma unroll
        for (int j = 0; j < 4; ++j){
          a0[j] = __builtin_amdgcn_mfma_f32_16x16x32_bf16(a_hi, whi[0][j][ks], a0[j], 0, 0, 0);
          a0[j] = __builtin_amdgcn_mfma_f32_16x16x32_bf16(a_lo, whi[0][j][ks], a0[j], 0, 0, 0);
          a0[j] = __builtin_amdgcn_mfma_f32_16x16x32_bf16(a_hi, wlo[0][j][ks], a0[j], 0, 0, 0);
          a1[j] = __builtin_amdgcn_mfma_f32_16x16x32_bf16(a_hi, whi[1][j][ks], a1[j], 0, 0, 0);
          a1[j] = __builtin_amdgcn_mfma_f32_16x16x32_bf16(a_lo, whi[1][j][ks], a1[j], 0, 0, 0);
          a1[j] = __builtin_amdgcn_mfma_f32_16x16x32_bf16(a_hi, wlo[1][j][ks], a1[j], 0, 0, 0);
        }
      }
    }
  };
  auto gates = [&](const f32x4* a, f32x4 pc, int cslot, bool has_prev,
                   bool has_del, int sg, ushort* outp, float* o3, f32x4& ncv_out){
    f32x4 dc;
    if (dil == 1) dc = pc;
    else dc = *(const f32x4*)(sh_c + cslot*CSLOT + sg*4);
    float whv[4];
    #pragma unroll
    for (int k = 0; k < 4; ++k){
      float f  = sigm(a[0][k] + 1.0f);
      float cd = tanh_fast(a[1][k]);
      float al = sigm(a[2][k]);
      float og = sigm(a[3][k]);
      float wt = has_del ? (al*pc[k] + (1.0f - al)*dc[k]) : pc[k];
      float nc = has_prev ? (f*wt + (1.0f - f)*cd) : cd;
      ncv_out[k] = nc;
      whv[k] = og * nc;
    }
    if (hi == 0){
      *(f32x4*)(sh_c + cslot*CSLOT + sg*4) = ncv_out;
      #pragma unroll
      for (int k = 0; k < 4; ++k){
        const float w = whv[k];
        if (sg < OUTC){
          if (stage == 3){
            o3[k*96 + sg] = w;
          } else {
            ushort hb = f2bf(w);
            outp[k*96 + sg]       = hb;
            outp[384 + k*96 + sg] = f2bf(w - bf2f(hb));
          }
        } else {
          ushort hb = f2bf(w);
          h_hi[(cslot*4 + k)*HS + (sg - OUTC)] = hb;
          h_lo[(cslot*4 + k)*HS + (sg - OUTC)] = f2bf(w - bf2f(hb));
        }
      }
    }
  };
  auto proj = [&](const ushort* outp, int s){
    f32x4 a1 = (f32x4){bav, bav, bav, bav};
    const int pbase = l15*96 + hi*8;
    #pragma unroll
    for (int ks = 0; ks < 3; ++ks){
      bf16x8 a_hi = *(const bf16x8*)(outp + pbase + ks*32);
      bf16x8 a_lo = *(const bf16x8*)(outp + 384 + pbase + ks*32);
      a1 = __builtin_amdgcn_mfma_f32_16x16x32_bf16(a_hi, phi[ks], a1, 0, 0, 0);
      a1 = __builtin_amdgcn_mfma_f32_16x16x32_bf16(a_lo, phi[ks], a1, 0, 0, 0);
      a1 = __builtin_amdgcn_mfma_f32_16x16x32_bf16(a_hi, plo[ks], a1, 0, 0, 0);
    }
    if (hi == 0){
      #pragma unroll
      for (int k = 0; k < 4; ++k)
        y_out[(size_t)(s*BATCH + b0r + k)*64 + ocol] = a1[k];
    }
  };

  __syncthreads();

  // ---- preloop: block until producer >= 4, load iteration-0 data ----
  u64 pfA_t = 0, pfA_u = 0, pfC_t = 0, pfC_u = 0;
  float xv_t = 0.0f, xv_u = 0.0f;
  uint fvU = 0, fvU1 = 0, fvDA = 0, fvDB = 0;
  if (stage == 0){
    xv_t = x[(size_t)(b0r + (tid>>6))*64 + (tid&63)];
    xv_u = x[(size_t)(BATCH + b0r + (tid>>6))*64 + (tid&63)];
  } else if (stage < 3){
    do { fvU = aload32(up_prod); if (fvU < 4u) __builtin_amdgcn_s_sleep(2); } while (fvU < 4u);
    if (tid < PAY){
      pfA_t = aload64(hop_in + (size_t)rep*PAY + tid);
      pfA_u = aload64(hop_in + (size_t)(NREP + rep)*PAY + tid);
    }
  } else {
    do { fvU  = aload32(up_prod);  if (fvU  < 4u) __builtin_amdgcn_s_sleep(2); } while (fvU  < 4u);
    do { fvU1 = aload32(up_prod1); if (fvU1 < 4u) __builtin_amdgcn_s_sleep(2); } while (fvU1 < 4u);
    if (tid < PAY){
      pfA_t = aload64(hop2 + (size_t)rep*PAY + tid);
      pfA_u = aload64(hop2 + (size_t)(NREP + rep)*PAY + tid);
      pfC_t = aload64(hop1 + (size_t)rep*PAY + tid);
      pfC_u = aload64(hop1 + (size_t)(NREP + rep)*PAY + tid);
    }
  }

  f32x4 ncvp0 = (f32x4){0.0f,0.0f,0.0f,0.0f};
  f32x4 ncvp1 = (f32x4){0.0f,0.0f,0.0f,0.0f};
  int cur_t = 0, prv_t = dil - 1;

  for (int it = 0; it < NITER; ++it){
    const int t = 2*it, u = t + 1;
    const int slot_t = t & rmask, slot_u = u & rmask;
    const int cur_u = (cur_t + 1 == dil) ? 0 : cur_t + 1;
    const int del_t = (t >= dil) ? cur_t : prv_t;
    const int del_u = (u >= dil) ? cur_u : cur_t;

    // ---- upstream optimistic check (sample is 1 iteration old) ----
    if (stage > 0){
      const bool bad = (fvU < (uint)(t+4)) || (stage == 3 && fvU1 < (uint)(t+4));
      if (bad){
        if (lane == 0){
          while (aload32(up_prod) < (uint)(t+2)) __builtin_amdgcn_s_sleep(2);
          if (stage == 3)
            while (aload32(up_prod1) < (uint)(t+2)) __builtin_amdgcn_s_sleep(2);
        }
        if (tid < PAY){
          if (stage < 3){
            pfA_t = aload64(hop_in + (size_t)(slot_t*NREP + rep)*PAY + tid);
            pfA_u = aload64(hop_in + (size_t)(slot_u*NREP + rep)*PAY + tid);
          } else {
            pfA_t = aload64(hop2 + (size_t)(slot_t*NREP + rep)*PAY + tid);
            pfA_u = aload64(hop2 + (size_t)(slot_u*NREP + rep)*PAY + tid);
            pfC_t = aload64(hop1 + (size_t)(slot_t*NREP + rep)*PAY + tid);
            pfC_u = aload64(hop1 + (size_t)(slot_u*NREP + rep)*PAY + tid);
          }
        }
      }
    }
    // ---- stage both steps' inputs ----
    if (stage == 0){
      const int r = tid >> 6, c = tid & 63;
      ushort hb = f2bf(xv_t);
      xiA_hi[r*XS + c] = hb; xiA_lo[r*XS + c] = f2bf(xv_t - bf2f(hb));
      hb = f2bf(xv_u);
      xiB_hi[r*XS + c] = hb; xiB_lo[r*XS + c] = f2bf(xv_u - bf2f(hb));
    } else {
      if (tid < PAY){
        const int q = (tid < 96) ? tid : tid - 96;
        const int off = (q/24)*XS + (q%24)*4;
        ushort* plA = (tid < 96) ? xiA_hi : xiA_lo;
        ushort* plB = (tid < 96) ? xiB_hi : xiB_lo;
        *(u64*)(plA + off) = pfA_t;
        *(u64*)(plB + off) = pfA_u;
        if (stage == 3){
          *(u64*)(o1pA + 4*tid) = pfC_t;
          *(u64*)(o1pB + 4*tid) = pfC_u;
        }
      }
    }
    __syncthreads();   // B1
    if (tid == 0){
      if (stage > 0){
        astore32(my_consA, (uint)(t+2));
        if (stage == 3) astore32(my_consB, (uint)(t+2));
      }
      if (stage < 3 && it >= 2) astore32(my_prod, (uint)(t-2));  // lag-2 proof
    }
    // ---- downstream-full check (never fires when rd >= T_STEPS) ----
    if (stage < 3 && u >= rd){
      const bool badc = (fvDA < (uint)(t+4-rd)) || (stage == 1 && fvDB < (uint)(t+4-rd));
      if (badc && lane == 0){
        while (aload32(dnA) < (uint)(t+2-rd)) __builtin_amdgcn_s_sleep(2);
        if (stage == 1)
          while (aload32(dnB) < (uint)(t+2-rd)) __builtin_amdgcn_s_sleep(2);
      }
    }
    // ---- issue prefetch for next iteration ----
    if (it + 1 < NITER){
      const int nt = (t+2) & rmask, nu = (t+3) & rmask;
      if (stage == 0){
        xv_t = x[(size_t)((t+2)*BATCH + b0r + (tid>>6))*64 + (tid&63)];
        xv_u = x[(size_t)((t+3)*BATCH + b0r + (tid>>6))*64 + (tid&63)];
      } else if (stage < 3){
        if (tid < PAY){
          pfA_t = aload64(hop_in + (size_t)(nt*NREP + rep)*PAY + tid);
          pfA_u = aload64(hop_in + (size_t)(nu*NREP + rep)*PAY + tid);
        }
        fvU = aload32(up_prod);
      } else {
        if (tid < PAY){
          pfA_t = aload64(hop2 + (size_t)(nt*NREP + rep)*PAY + tid);
          pfA_u = aload64(hop2 + (size_t)(nu*NREP + rep)*PAY + tid);
          pfC_t = aload64(hop1 + (size_t)(nt*NREP + rep)*PAY + tid);
          pfC_u = aload64(hop1 + (size_t)(nu*NREP + rep)*PAY + tid);
        }
        fvU  = aload32(up_prod);
        fvU1 = aload32(up_prod1);
      }
    }
    if (stage < 3) fvDA = aload32(dnA);
    if (stage == 1) fvDB = aload32(dnB);
    asm volatile("" ::: "memory");

    // ---- STEP t ----
    f32x4 a0[4], a1v[4];
    #pragma unroll
    for (int j = 0; j < 4; ++j){
      a0[j]  = (f32x4){bias[0][j],bias[0][j],bias[0][j],bias[0][j]};
      a1v[j] = (f32x4){bias[1][j],bias[1][j],bias[1][j],bias[1][j]};
    }
    gemm(xiA_hi, xiA_lo, prv_t, del_t, a0, a1v);
    f32x4 n0, n1;
    gates(a0,  ncvp0, cur_t, (t >= 1), (t >= dil), sidx,      outpA, o3fA, n0);
    gates(a1v, ncvp1, cur_t, (t >= 1), (t >= dil), sidx + 16, outpA, o3fA, n1);
    ncvp0 = n0; ncvp1 = n1;
    __syncthreads();   // Bmid

    if (stage == 3){
      for (int j = tid; j < 384; j += 256){
        float v = o3fA[j] + bf2f(o1pA[j]) + bf2f(o1pA[384 + j]);
        ushort hb = f2bf(v);
        outpA[j]       = hb;
        outpA[384 + j] = f2bf(v - bf2f(hb));
      }
    }
    // ---- STEP u ----
    #pragma unroll
    for (int j = 0; j < 4; ++j){
      a0[j]  = (f32x4){bias[0][j],bias[0][j],bias[0][j],bias[0][j]};
      a1v[j] = (f32x4){bias[1][j],bias[1][j],bias[1][j],bias[1][j]};
    }
    gemm(xiB_hi, xiB_lo, cur_t, del_u, a0, a1v);
    gates(a0,  ncvp0, cur_u, true, (u >= dil), sidx,      outpB, o3fB, n0);
    gates(a1v, ncvp1, cur_u, true, (u >= dil), sidx + 16, outpB, o3fB, n1);
    ncvp0 = n0; ncvp1 = n1;
    __syncthreads();   // B2

    if (stage < 3){
      if (tid < PAY){
        astore64(hop_out + (size_t)(slot_t*NREP + rep)*PAY + tid, *(const u64*)(outpA + 4*tid));
        astore64(hop_out + (size_t)(slot_u*NREP + rep)*PAY + tid, *(const u64*)(outpB + 4*tid));
      }
    } else {
      proj(outpA, t);   // outpA stable after B2
      for (int j = tid; j < 384; j += 256){
        float v = o3fB[j] + bf2f(o1pB[j]) + bf2f(o1pB[384 + j]);
        ushort hb = f2bf(v);
        outpB[j]       = hb;
        outpB[384 + j] = f2bf(v - bf2f(hb));
      }
      __syncthreads(); // B3u
      proj(outpB, u);
    }
    prv_t = cur_u;
    cur_t = (cur_u + 1 == dil) ? 0 : cur_u + 1;
  }

  // ---- postloop: drain all stores, terminal flags ----
  asm volatile("s_waitcnt vmcnt(0)" ::: "memory");
  __syncthreads();
  if (stage < 3 && tid == 0) astore32(my_prod, (uint)(T_STEPS + 8));
}

extern "C" void kernel_launch(void* const* d_in, const int* in_sizes, int n_in,
                              void* d_out, int out_size, void* d_ws, size_t ws_size,
                              hipStream_t stream) {
  (void)in_sizes; (void)n_in; (void)out_size;
  const float* x  = (const float*)d_in[0];
  const float* W0 = (const float*)d_in[1];
  const float* b0 = (const float*)d_in[2];
  const float* W1 = (const float*)d_in[3];
  const float* b1 = (const float*)d_in[4];
  const float* W2 = (const float*)d_in[5];
  const float* b2 = (const float*)d_in[6];
  const float* W3 = (const float*)d_in[7];
  const float* b3 = (const float*)d_in[8];
  const float* Wa = (const float*)d_in[9];
  const float* ba = (const float*)d_in[10];
  float* out = (float*)d_out;

  // Flags: prod[3][128] @0 (49152B), consA[3][128] @49152, consB[128] @98304.
  // Rings @114688: [rd][128 reps][192 u64] per hop.
  const size_t RING_OFF = 114688;
  int rd = 16;
  if (ws_size > RING_OFF){
    size_t avail = ws_size - RING_OFF;
    while (rd < 512 && (size_t)(rd * 2) * 128 * 4608 <= avail) rd *= 2;
  }

  uint* prod  = (uint*)d_ws;
  uint* consA = (uint*)((char*)d_ws + 49152);
  uint* consB = (uint*)((char*)d_ws + 98304);
  u64* hop0 = (u64*)((char*)d_ws + RING_OFF);
  u64* hop1 = hop0 + (size_t)rd*128*192;
  u64* hop2 = hop1 + (size_t)rd*128*192;

  hipMemsetAsync(d_ws, 0, RING_OFF, stream);  // re-zero flags every call
  hipLaunchKernelGGL(rnn_pipeline, dim3(512), dim3(256), 0, stream,
                     x, W0, b0, W1, b1, W2, b2, W3, b3, Wa, ba,
                     out, prod, consA, consB, hop0, hop1, hop2, rd);
}